// Round 1
// baseline (1006.722 us; speedup 1.0000x reference)
//
#include <hip/hip_runtime.h>
#include <math.h>

#define NTOK   32768
#define DMODEL 512
#define HIDDEN 2048
#define NEXP   16
#define TM     128
#define TN     128
#define BK     64
#define MAXT   272
#define PADN   (MAXT * TM)

typedef short bf16x8 __attribute__((ext_vector_type(8)));
typedef float f32x4  __attribute__((ext_vector_type(4)));

__device__ __forceinline__ short f2bf(float f) {
  union { float f; unsigned int u; } v; v.f = f;
  unsigned int r = v.u + 0x7FFFu + ((v.u >> 16) & 1u);   // RNE
  return (short)(r >> 16);
}

__device__ __forceinline__ void gload_lds16(const void* g, void* l) {
  __builtin_amdgcn_global_load_lds(
      (const __attribute__((address_space(1))) void*)g,
      (__attribute__((address_space(3))) void*)l, 16, 0, 0);
}

// ---------------------------------------------------------------- init
__global__ void init_kernel(int* counts, int* cursors) {
  if (threadIdx.x < NEXP) { counts[threadIdx.x] = 0; cursors[threadIdx.x] = 0; }
}

// ---------------------------------------------------------------- route (+ x -> bf16)
// 1 wave per token; fp64 logit accumulation so routing decisions match the
// exact value (a flipped decision = O(1) output error).
__global__ __launch_bounds__(256) void route_kernel(
    const float* __restrict__ x, const float* __restrict__ Wr,
    const float* __restrict__ br, short* __restrict__ xb,
    int* __restrict__ leafArr, int* __restrict__ counts) {
  const int w = threadIdx.x >> 6, l = threadIdx.x & 63;
  const int tok = blockIdx.x * 4 + w;
  const float4* xr = (const float4*)(x + (size_t)tok * DMODEL);
  float4 a0 = xr[l * 2], a1 = xr[l * 2 + 1];

  union { bf16x8 v; short s[8]; } u;
  u.s[0] = f2bf(a0.x); u.s[1] = f2bf(a0.y); u.s[2] = f2bf(a0.z); u.s[3] = f2bf(a0.w);
  u.s[4] = f2bf(a1.x); u.s[5] = f2bf(a1.y); u.s[6] = f2bf(a1.z); u.s[7] = f2bf(a1.w);
  *((bf16x8*)(xb + (size_t)tok * DMODEL) + l) = u.v;

  int leaf = 0;
  for (int d = 0; d < 4; ++d) {
    const int node = (1 << d) - 1 + leaf;
    const float4* wr4 = (const float4*)(Wr + (size_t)node * DMODEL);
    float4 b0 = wr4[l * 2], b1v = wr4[l * 2 + 1];
    double s = (double)a0.x * (double)b0.x + (double)a0.y * (double)b0.y +
               (double)a0.z * (double)b0.z + (double)a0.w * (double)b0.w +
               (double)a1.x * (double)b1v.x + (double)a1.y * (double)b1v.y +
               (double)a1.z * (double)b1v.z + (double)a1.w * (double)b1v.w;
    for (int off = 32; off; off >>= 1) s += __shfl_xor(s, off);
    double sel = s + (double)br[node];
    leaf = leaf * 2 + (sel > 0.0 ? 1 : 0);
  }
  if (l == 0) { leafArr[tok] = leaf; atomicAdd(&counts[leaf], 1); }
}

// ---------------------------------------------------------------- scan (1 block)
__global__ void scan_kernel(const int* __restrict__ counts, int* poff, int* ntiles,
                            int* texp, int* tval, int* idx) {
  if (threadIdx.x == 0) {
    int po = 0, nt = 0;
    for (int e = 0; e < NEXP; ++e) {
      poff[e] = po;
      const int c = counts[e];
      const int t = (c + TM - 1) >> 7;
      for (int i = 0; i < t; ++i) {
        texp[nt] = e;
        int v = c - i * TM; if (v > TM) v = TM;
        tval[nt] = v;
        ++nt;
      }
      po += t << 7;
    }
    poff[NEXP] = po;
    *ntiles = nt;
  }
  __syncthreads();
  for (int i = threadIdx.x; i < PADN; i += blockDim.x) idx[i] = 0;  // pad rows -> token 0
}

// ---------------------------------------------------------------- scatter
__global__ __launch_bounds__(256) void scatter_kernel(
    const int* __restrict__ leafArr, const int* __restrict__ poff,
    int* cursors, int* __restrict__ idx) {
  __shared__ int lcnt[NEXP], lbase[NEXP];
  const int tid = threadIdx.x;
  if (tid < NEXP) lcnt[tid] = 0;
  __syncthreads();
  const int tok = blockIdx.x * 256 + tid;
  const int e = leafArr[tok];
  const int r = atomicAdd(&lcnt[e], 1);
  __syncthreads();
  if (tid < NEXP) lbase[tid] = lcnt[tid] ? atomicAdd(&cursors[tid], lcnt[tid]) : 0;
  __syncthreads();
  idx[poff[e] + lbase[e] + r] = tok;
}

// ---------------------------------------------------------------- transpose+convert
// src [E][R][C] f32 -> dst [E][C][R] bf16  (MFMA B-operand wants K-contiguous rows)
__global__ void tconv_kernel(const float* __restrict__ src, short* __restrict__ dst,
                             int R, int C) {
  __shared__ float tile[32][33];
  const int tx = threadIdx.x, ty = threadIdx.y;
  const int c0 = blockIdx.x * 32, r0 = blockIdx.y * 32;
  const size_t eoff = (size_t)blockIdx.z * R * C;
  for (int i = 0; i < 4; ++i)
    tile[ty + i * 8][tx] = src[eoff + (size_t)(r0 + ty + i * 8) * C + c0 + tx];
  __syncthreads();
  for (int i = 0; i < 4; ++i)
    dst[eoff + (size_t)(c0 + ty + i * 8) * R + r0 + tx] = f2bf(tile[tx][ty + i * 8]);
}

// ---------------------------------------------------------------- GEMM1: H = GELU(Xg @ W1 + b1)
__global__ __launch_bounds__(256) void gemm1_kernel(
    const short* __restrict__ Xb, const short* __restrict__ W1T,
    const float* __restrict__ b1, const int* __restrict__ idx,
    const int* __restrict__ texp, const int* __restrict__ ntiles,
    short* __restrict__ H, int g0) {
  const int lt = blockIdx.x;
  const int t = g0 + lt;
  if (t >= *ntiles) return;
  const int e = texp[t];
  const int c0 = blockIdx.y * TN;

  __shared__ short As[TM * BK];
  __shared__ short Bs[TN * BK];

  const int tid = threadIdx.x, w = tid >> 6, lane = tid & 63;
  const int q = lane >> 4, cc = lane & 15;
  const int wr = (w >> 1) * 64, wc = (w & 1) * 64;
  const int srow = lane >> 3, skk = (lane & 7) * 8;

  f32x4 acc[4][4];
  const f32x4 zero = {0.f, 0.f, 0.f, 0.f};
  for (int mi = 0; mi < 4; ++mi)
    for (int ni = 0; ni < 4; ++ni) acc[mi][ni] = zero;

  for (int k0 = 0; k0 < DMODEL; k0 += BK) {
    __syncthreads();
    for (int ii = 0; ii < 4; ++ii) {
      const int i = w * 4 + ii;
      const int trow = i * 8 + srow;
      const int gt = idx[t * TM + trow];                    // gathered token (pads -> 0)
      gload_lds16(Xb + (size_t)gt * DMODEL + k0 + skk, As + i * 512);
      const int nn = c0 + i * 8 + srow;
      gload_lds16(W1T + ((size_t)e * HIDDEN + nn) * DMODEL + k0 + skk, Bs + i * 512);
    }
    __syncthreads();
    for (int ki = 0; ki < 2; ++ki) {
      const int kof = ki * 32 + q * 8;
      bf16x8 af[4], bfv[4];
      for (int mi = 0; mi < 4; ++mi)
        af[mi] = *(const bf16x8*)(As + (wr + mi * 16 + cc) * BK + kof);
      for (int ni = 0; ni < 4; ++ni)
        bfv[ni] = *(const bf16x8*)(Bs + (wc + ni * 16 + cc) * BK + kof);
      for (int mi = 0; mi < 4; ++mi)
        for (int ni = 0; ni < 4; ++ni)
          acc[mi][ni] = __builtin_amdgcn_mfma_f32_16x16x32_bf16(af[mi], bfv[ni], acc[mi][ni], 0, 0, 0);
    }
  }

  for (int ni = 0; ni < 4; ++ni) {
    const int col = c0 + wc + ni * 16 + cc;
    const float bv = b1[e * HIDDEN + col];
    for (int mi = 0; mi < 4; ++mi) {
      for (int r = 0; r < 4; ++r) {
        const int row = wr + mi * 16 + q * 4 + r;
        float v = acc[mi][ni][r] + bv;
        v = 0.5f * v * (1.0f + erff(v * 0.70710678118654752f));   // exact GELU
        H[((size_t)lt * TM + row) * HIDDEN + col] = f2bf(v);
      }
    }
  }
}

// ---------------------------------------------------------------- GEMM2: out[tok] = H @ W2 + b2
__global__ __launch_bounds__(256) void gemm2_kernel(
    const short* __restrict__ H, const short* __restrict__ W2T,
    const float* __restrict__ b2, const int* __restrict__ idx,
    const int* __restrict__ texp, const int* __restrict__ tval,
    const int* __restrict__ ntiles, float* __restrict__ out, int g0) {
  const int lt = blockIdx.x;
  const int t = g0 + lt;
  if (t >= *ntiles) return;
  const int e = texp[t];
  const int c0 = blockIdx.y * TN;   // 0..511 in steps of 128

  __shared__ short As[TM * BK];
  __shared__ short Bs[TN * BK];

  const int tid = threadIdx.x, w = tid >> 6, lane = tid & 63;
  const int q = lane >> 4, cc = lane & 15;
  const int wr = (w >> 1) * 64, wc = (w & 1) * 64;
  const int srow = lane >> 3, skk = (lane & 7) * 8;

  f32x4 acc[4][4];
  const f32x4 zero = {0.f, 0.f, 0.f, 0.f};
  for (int mi = 0; mi < 4; ++mi)
    for (int ni = 0; ni < 4; ++ni) acc[mi][ni] = zero;

  for (int k0 = 0; k0 < HIDDEN; k0 += BK) {
    __syncthreads();
    for (int ii = 0; ii < 4; ++ii) {
      const int i = w * 4 + ii;
      const int trow = i * 8 + srow;
      gload_lds16(H + ((size_t)lt * TM + trow) * HIDDEN + k0 + skk, As + i * 512);
      const int nn = c0 + i * 8 + srow;
      gload_lds16(W2T + ((size_t)e * DMODEL + nn) * HIDDEN + k0 + skk, Bs + i * 512);
    }
    __syncthreads();
    for (int ki = 0; ki < 2; ++ki) {
      const int kof = ki * 32 + q * 8;
      bf16x8 af[4], bfv[4];
      for (int mi = 0; mi < 4; ++mi)
        af[mi] = *(const bf16x8*)(As + (wr + mi * 16 + cc) * BK + kof);
      for (int ni = 0; ni < 4; ++ni)
        bfv[ni] = *(const bf16x8*)(Bs + (wc + ni * 16 + cc) * BK + kof);
      for (int mi = 0; mi < 4; ++mi)
        for (int ni = 0; ni < 4; ++ni)
          acc[mi][ni] = __builtin_amdgcn_mfma_f32_16x16x32_bf16(af[mi], bfv[ni], acc[mi][ni], 0, 0, 0);
    }
  }

  const int nv = tval[t];
  for (int ni = 0; ni < 4; ++ni) {
    const int col = c0 + wc + ni * 16 + cc;
    const float bv = b2[e * DMODEL + col];
    for (int mi = 0; mi < 4; ++mi) {
      for (int r = 0; r < 4; ++r) {
        const int row = wr + mi * 16 + q * 4 + r;
        if (row < nv) {
          const int tok = idx[t * TM + row];
          out[(size_t)tok * DMODEL + col] = acc[mi][ni][r] + bv;
        }
      }
    }
  }
}

// ---------------------------------------------------------------- host
extern "C" void kernel_launch(void* const* d_in, const int* in_sizes, int n_in,
                              void* d_out, int out_size, void* d_ws, size_t ws_size,
                              hipStream_t stream) {
  (void)in_sizes; (void)n_in; (void)out_size;
  const float* x  = (const float*)d_in[0];
  const float* Wr = (const float*)d_in[1];
  const float* br = (const float*)d_in[2];
  const float* W1 = (const float*)d_in[3];
  const float* b1 = (const float*)d_in[4];
  const float* W2 = (const float*)d_in[5];
  const float* b2 = (const float*)d_in[6];
  float* out = (float*)d_out;
  char* ws = (char*)d_ws;

  int* counts  = (int*)(ws + 0);
  int* cursors = (int*)(ws + 256);
  int* poff    = (int*)(ws + 512);
  int* ntiles  = (int*)(ws + 768);
  int* texp    = (int*)(ws + 1024);
  int* tval    = (int*)(ws + 4096);
  int* leafA   = (int*)(ws + 8192);
  int* idx     = (int*)(ws + 8192 + 131072);

  const size_t MB32 = 33554432ull;
  short* Xb  = (short*)(ws + (1ull << 20));
  short* W1T = (short*)(ws + (1ull << 20) + MB32);
  short* W2T = (short*)(ws + (1ull << 20) + 2 * MB32);
  short* Hb  = (short*)(ws + (1ull << 20) + 3 * MB32);
  const size_t o_h = (1ull << 20) + 3 * MB32;
  const size_t perTile = (size_t)TM * HIDDEN * sizeof(short);   // 512 KB

  int TPG = MAXT;
  if (ws_size < o_h + (size_t)MAXT * perTile) {
    size_t avail = ws_size > o_h ? ws_size - o_h : 0;
    TPG = (int)(avail / perTile);
    if (TPG < 1) TPG = 1;
  }
  const int ngroups = (MAXT + TPG - 1) / TPG;

  hipLaunchKernelGGL(init_kernel,    dim3(1),          dim3(64),    0, stream, counts, cursors);
  hipLaunchKernelGGL(route_kernel,   dim3(NTOK / 4),   dim3(256),   0, stream, x, Wr, br, Xb, leafA, counts);
  hipLaunchKernelGGL(scan_kernel,    dim3(1),          dim3(256),   0, stream, counts, poff, ntiles, texp, tval, idx);
  hipLaunchKernelGGL(scatter_kernel, dim3(NTOK / 256), dim3(256),   0, stream, leafA, poff, cursors, idx);
  hipLaunchKernelGGL(tconv_kernel,   dim3(64, 16, 16), dim3(32, 8), 0, stream, W1, W1T, DMODEL, HIDDEN);
  hipLaunchKernelGGL(tconv_kernel,   dim3(16, 64, 16), dim3(32, 8), 0, stream, W2, W2T, HIDDEN, DMODEL);

  for (int g = 0; g < ngroups; ++g) {
    hipLaunchKernelGGL(gemm1_kernel, dim3(TPG, HIDDEN / TN), dim3(256), 0, stream,
                       Xb, W1T, b1, idx, texp, ntiles, Hb, g * TPG);
    hipLaunchKernelGGL(gemm2_kernel, dim3(TPG, DMODEL / TN), dim3(256), 0, stream,
                       Hb, W2T, b2, idx, texp, tval, ntiles, out, g * TPG);
  }
}

// Round 2
// 659.021 us; speedup vs baseline: 1.5276x; 1.5276x over previous
//
#include <hip/hip_runtime.h>
#include <math.h>

#define NTOK   32768
#define DMODEL 512
#define HIDDEN 2048
#define NEXP   16
#define TM     128
#define TN     128
#define BK     64
#define MAXT   272
#define PADN   (MAXT * TM)
#define CPAD   16              // pad per-expert counters to one 64B line

typedef short bf16x8 __attribute__((ext_vector_type(8)));
typedef float f32x4  __attribute__((ext_vector_type(4)));

__device__ __forceinline__ short f2bf(float f) {
  union { float f; unsigned int u; } v; v.f = f;
  unsigned int r = v.u + 0x7FFFu + ((v.u >> 16) & 1u);   // RNE
  return (short)(r >> 16);
}

__device__ __forceinline__ void gload_lds16(const void* g, void* l) {
  __builtin_amdgcn_global_load_lds(
      (const __attribute__((address_space(1))) void*)g,
      (__attribute__((address_space(3))) void*)l, 16, 0, 0);
}

// ---------------------------------------------------------------- init
__global__ void init_kernel(int* counts, int* cursors) {
  counts[threadIdx.x] = 0; cursors[threadIdx.x] = 0;   // 256 padded ints each
}

// ---------------------------------------------------------------- route (+ x -> bf16)
// 1 wave per token; fp64 logit accumulation so routing decisions match the
// exact value (a flipped decision = O(1) output error). NO atomics here —
// the 16-counter single-cache-line atomic was 28 cyc/RMW serialized = 381 us.
__global__ __launch_bounds__(256) void route_kernel(
    const float* __restrict__ x, const float* __restrict__ Wr,
    const float* __restrict__ br, short* __restrict__ xb,
    int* __restrict__ leafArr) {
  const int w = threadIdx.x >> 6, l = threadIdx.x & 63;
  const int tok = blockIdx.x * 4 + w;
  const float4* xr = (const float4*)(x + (size_t)tok * DMODEL);
  float4 a0 = xr[l * 2], a1 = xr[l * 2 + 1];

  union { bf16x8 v; short s[8]; } u;
  u.s[0] = f2bf(a0.x); u.s[1] = f2bf(a0.y); u.s[2] = f2bf(a0.z); u.s[3] = f2bf(a0.w);
  u.s[4] = f2bf(a1.x); u.s[5] = f2bf(a1.y); u.s[6] = f2bf(a1.z); u.s[7] = f2bf(a1.w);
  *((bf16x8*)(xb + (size_t)tok * DMODEL) + l) = u.v;

  int leaf = 0;
  for (int d = 0; d < 4; ++d) {
    const int node = (1 << d) - 1 + leaf;
    const float4* wr4 = (const float4*)(Wr + (size_t)node * DMODEL);
    float4 b0 = wr4[l * 2], b1v = wr4[l * 2 + 1];
    double s = (double)a0.x * (double)b0.x + (double)a0.y * (double)b0.y +
               (double)a0.z * (double)b0.z + (double)a0.w * (double)b0.w +
               (double)a1.x * (double)b1v.x + (double)a1.y * (double)b1v.y +
               (double)a1.z * (double)b1v.z + (double)a1.w * (double)b1v.w;
    for (int off = 32; off; off >>= 1) s += __shfl_xor(s, off);
    double sel = s + (double)br[node];
    leaf = leaf * 2 + (sel > 0.0 ? 1 : 0);
  }
  if (l == 0) leafArr[tok] = leaf;
}

// ---------------------------------------------------------------- count
// Block-local histogram -> one padded-line atomic per expert per block.
// Also zero-fills idx (pad rows -> token 0) before scatter runs.
__global__ __launch_bounds__(256) void count_kernel(
    const int* __restrict__ leafArr, int* __restrict__ counts,
    int* __restrict__ idx) {
  __shared__ int lcnt[NEXP];
  const int tid = threadIdx.x;
  if (tid < NEXP) lcnt[tid] = 0;
  __syncthreads();
  const int tok = blockIdx.x * 256 + tid;
  atomicAdd(&lcnt[leafArr[tok]], 1);
  __syncthreads();
  if (tid < NEXP && lcnt[tid]) atomicAdd(&counts[tid * CPAD], lcnt[tid]);
  for (int i = blockIdx.x * 256 + tid; i < PADN; i += gridDim.x * 256) idx[i] = 0;
}

// ---------------------------------------------------------------- scan (1 block)
__global__ void scan_kernel(const int* __restrict__ counts, int* poff, int* ntiles,
                            int* texp, int* tval) {
  if (threadIdx.x == 0) {
    int po = 0, nt = 0;
    for (int e = 0; e < NEXP; ++e) {
      poff[e] = po;
      const int c = counts[e * CPAD];
      const int t = (c + TM - 1) >> 7;
      for (int i = 0; i < t; ++i) {
        texp[nt] = e;
        int v = c - i * TM; if (v > TM) v = TM;
        tval[nt] = v;
        ++nt;
      }
      po += t << 7;
    }
    poff[NEXP] = po;
    *ntiles = nt;
  }
}

// ---------------------------------------------------------------- scatter
__global__ __launch_bounds__(256) void scatter_kernel(
    const int* __restrict__ leafArr, const int* __restrict__ poff,
    int* cursors, int* __restrict__ idx) {
  __shared__ int lcnt[NEXP], lbase[NEXP];
  const int tid = threadIdx.x;
  if (tid < NEXP) lcnt[tid] = 0;
  __syncthreads();
  const int tok = blockIdx.x * 256 + tid;
  const int e = leafArr[tok];
  const int r = atomicAdd(&lcnt[e], 1);
  __syncthreads();
  if (tid < NEXP) lbase[tid] = lcnt[tid] ? atomicAdd(&cursors[tid * CPAD], lcnt[tid]) : 0;
  __syncthreads();
  idx[poff[e] + lbase[e] + r] = tok;
}

// ---------------------------------------------------------------- transpose+convert
// src [E][R][C] f32 -> dst [E][C][R] bf16  (MFMA B-operand wants K-contiguous rows)
__global__ void tconv_kernel(const float* __restrict__ src, short* __restrict__ dst,
                             int R, int C) {
  __shared__ float tile[32][33];
  const int tx = threadIdx.x, ty = threadIdx.y;
  const int c0 = blockIdx.x * 32, r0 = blockIdx.y * 32;
  const size_t eoff = (size_t)blockIdx.z * R * C;
  for (int i = 0; i < 4; ++i)
    tile[ty + i * 8][tx] = src[eoff + (size_t)(r0 + ty + i * 8) * C + c0 + tx];
  __syncthreads();
  for (int i = 0; i < 4; ++i)
    dst[eoff + (size_t)(c0 + ty + i * 8) * R + r0 + tx] = f2bf(tile[tx][ty + i * 8]);
}

// ---------------------------------------------------------------- GEMM1: H = GELU(Xg @ W1 + b1)
__global__ __launch_bounds__(256) void gemm1_kernel(
    const short* __restrict__ Xb, const short* __restrict__ W1T,
    const float* __restrict__ b1, const int* __restrict__ idx,
    const int* __restrict__ texp, const int* __restrict__ ntiles,
    short* __restrict__ H, int g0) {
  const int lt = blockIdx.x;
  const int t = g0 + lt;
  if (t >= *ntiles) return;
  const int e = texp[t];
  const int c0 = blockIdx.y * TN;

  __shared__ short As[TM * BK];
  __shared__ short Bs[TN * BK];

  const int tid = threadIdx.x, w = tid >> 6, lane = tid & 63;
  const int q = lane >> 4, cc = lane & 15;
  const int wr = (w >> 1) * 64, wc = (w & 1) * 64;
  const int srow = lane >> 3, skk = (lane & 7) * 8;

  f32x4 acc[4][4];
  const f32x4 zero = {0.f, 0.f, 0.f, 0.f};
  for (int mi = 0; mi < 4; ++mi)
    for (int ni = 0; ni < 4; ++ni) acc[mi][ni] = zero;

  for (int k0 = 0; k0 < DMODEL; k0 += BK) {
    __syncthreads();
    for (int ii = 0; ii < 4; ++ii) {
      const int i = w * 4 + ii;
      const int trow = i * 8 + srow;
      const int gt = idx[t * TM + trow];                    // gathered token (pads -> 0)
      gload_lds16(Xb + (size_t)gt * DMODEL + k0 + skk, As + i * 512);
      const int nn = c0 + i * 8 + srow;
      gload_lds16(W1T + ((size_t)e * HIDDEN + nn) * DMODEL + k0 + skk, Bs + i * 512);
    }
    __syncthreads();
    for (int ki = 0; ki < 2; ++ki) {
      const int kof = ki * 32 + q * 8;
      bf16x8 af[4], bfv[4];
      for (int mi = 0; mi < 4; ++mi)
        af[mi] = *(const bf16x8*)(As + (wr + mi * 16 + cc) * BK + kof);
      for (int ni = 0; ni < 4; ++ni)
        bfv[ni] = *(const bf16x8*)(Bs + (wc + ni * 16 + cc) * BK + kof);
      for (int mi = 0; mi < 4; ++mi)
        for (int ni = 0; ni < 4; ++ni)
          acc[mi][ni] = __builtin_amdgcn_mfma_f32_16x16x32_bf16(af[mi], bfv[ni], acc[mi][ni], 0, 0, 0);
    }
  }

  for (int ni = 0; ni < 4; ++ni) {
    const int col = c0 + wc + ni * 16 + cc;
    const float bv = b1[e * HIDDEN + col];
    for (int mi = 0; mi < 4; ++mi) {
      for (int r = 0; r < 4; ++r) {
        const int row = wr + mi * 16 + q * 4 + r;
        float v = acc[mi][ni][r] + bv;
        v = 0.5f * v * (1.0f + erff(v * 0.70710678118654752f));   // exact GELU
        H[((size_t)lt * TM + row) * HIDDEN + col] = f2bf(v);
      }
    }
  }
}

// ---------------------------------------------------------------- GEMM2: out[tok] = H @ W2 + b2
__global__ __launch_bounds__(256) void gemm2_kernel(
    const short* __restrict__ H, const short* __restrict__ W2T,
    const float* __restrict__ b2, const int* __restrict__ idx,
    const int* __restrict__ texp, const int* __restrict__ tval,
    const int* __restrict__ ntiles, float* __restrict__ out, int g0) {
  const int lt = blockIdx.x;
  const int t = g0 + lt;
  if (t >= *ntiles) return;
  const int e = texp[t];
  const int c0 = blockIdx.y * TN;   // 0..511 in steps of 128

  __shared__ short As[TM * BK];
  __shared__ short Bs[TN * BK];

  const int tid = threadIdx.x, w = tid >> 6, lane = tid & 63;
  const int q = lane >> 4, cc = lane & 15;
  const int wr = (w >> 1) * 64, wc = (w & 1) * 64;
  const int srow = lane >> 3, skk = (lane & 7) * 8;

  f32x4 acc[4][4];
  const f32x4 zero = {0.f, 0.f, 0.f, 0.f};
  for (int mi = 0; mi < 4; ++mi)
    for (int ni = 0; ni < 4; ++ni) acc[mi][ni] = zero;

  for (int k0 = 0; k0 < HIDDEN; k0 += BK) {
    __syncthreads();
    for (int ii = 0; ii < 4; ++ii) {
      const int i = w * 4 + ii;
      const int trow = i * 8 + srow;
      gload_lds16(H + ((size_t)lt * TM + trow) * HIDDEN + k0 + skk, As + i * 512);
      const int nn = c0 + i * 8 + srow;
      gload_lds16(W2T + ((size_t)e * DMODEL + nn) * HIDDEN + k0 + skk, Bs + i * 512);
    }
    __syncthreads();
    for (int ki = 0; ki < 2; ++ki) {
      const int kof = ki * 32 + q * 8;
      bf16x8 af[4], bfv[4];
      for (int mi = 0; mi < 4; ++mi)
        af[mi] = *(const bf16x8*)(As + (wr + mi * 16 + cc) * BK + kof);
      for (int ni = 0; ni < 4; ++ni)
        bfv[ni] = *(const bf16x8*)(Bs + (wc + ni * 16 + cc) * BK + kof);
      for (int mi = 0; mi < 4; ++mi)
        for (int ni = 0; ni < 4; ++ni)
          acc[mi][ni] = __builtin_amdgcn_mfma_f32_16x16x32_bf16(af[mi], bfv[ni], acc[mi][ni], 0, 0, 0);
    }
  }

  const int nv = tval[t];
  for (int ni = 0; ni < 4; ++ni) {
    const int col = c0 + wc + ni * 16 + cc;
    const float bv = b2[e * DMODEL + col];
    for (int mi = 0; mi < 4; ++mi) {
      for (int r = 0; r < 4; ++r) {
        const int row = wr + mi * 16 + q * 4 + r;
        if (row < nv) {
          const int tok = idx[t * TM + row];
          out[(size_t)tok * DMODEL + col] = acc[mi][ni][r] + bv;
        }
      }
    }
  }
}

// ---------------------------------------------------------------- host
extern "C" void kernel_launch(void* const* d_in, const int* in_sizes, int n_in,
                              void* d_out, int out_size, void* d_ws, size_t ws_size,
                              hipStream_t stream) {
  (void)in_sizes; (void)n_in; (void)out_size;
  const float* x  = (const float*)d_in[0];
  const float* Wr = (const float*)d_in[1];
  const float* br = (const float*)d_in[2];
  const float* W1 = (const float*)d_in[3];
  const float* b1 = (const float*)d_in[4];
  const float* W2 = (const float*)d_in[5];
  const float* b2 = (const float*)d_in[6];
  float* out = (float*)d_out;
  char* ws = (char*)d_ws;

  int* counts  = (int*)(ws + 0);        // 256 ints, padded x16
  int* cursors = (int*)(ws + 1024);     // 256 ints, padded x16
  int* poff    = (int*)(ws + 2048);
  int* ntiles  = (int*)(ws + 2304);
  int* texp    = (int*)(ws + 4096);
  int* tval    = (int*)(ws + 8192);
  int* leafA   = (int*)(ws + 16384);
  int* idx     = (int*)(ws + 16384 + 131072);

  const size_t MB32 = 33554432ull;
  short* Xb  = (short*)(ws + (1ull << 20));
  short* W1T = (short*)(ws + (1ull << 20) + MB32);
  short* W2T = (short*)(ws + (1ull << 20) + 2 * MB32);
  short* Hb  = (short*)(ws + (1ull << 20) + 3 * MB32);
  const size_t o_h = (1ull << 20) + 3 * MB32;
  const size_t perTile = (size_t)TM * HIDDEN * sizeof(short);   // 512 KB

  int TPG = MAXT;
  if (ws_size < o_h + (size_t)MAXT * perTile) {
    size_t avail = ws_size > o_h ? ws_size - o_h : 0;
    TPG = (int)(avail / perTile);
    if (TPG < 1) TPG = 1;
  }
  const int ngroups = (MAXT + TPG - 1) / TPG;

  hipLaunchKernelGGL(init_kernel,    dim3(1),          dim3(256),   0, stream, counts, cursors);
  hipLaunchKernelGGL(route_kernel,   dim3(NTOK / 4),   dim3(256),   0, stream, x, Wr, br, Xb, leafA);
  hipLaunchKernelGGL(count_kernel,   dim3(NTOK / 256), dim3(256),   0, stream, leafA, counts, idx);
  hipLaunchKernelGGL(scan_kernel,    dim3(1),          dim3(64),    0, stream, counts, poff, ntiles, texp, tval);
  hipLaunchKernelGGL(scatter_kernel, dim3(NTOK / 256), dim3(256),   0, stream, leafA, poff, cursors, idx);
  hipLaunchKernelGGL(tconv_kernel,   dim3(64, 16, 16), dim3(32, 8), 0, stream, W1, W1T, DMODEL, HIDDEN);
  hipLaunchKernelGGL(tconv_kernel,   dim3(16, 64, 16), dim3(32, 8), 0, stream, W2, W2T, HIDDEN, DMODEL);

  for (int g = 0; g < ngroups; ++g) {
    hipLaunchKernelGGL(gemm1_kernel, dim3(TPG, HIDDEN / TN), dim3(256), 0, stream,
                       Xb, W1T, b1, idx, texp, ntiles, Hb, g * TPG);
    hipLaunchKernelGGL(gemm2_kernel, dim3(TPG, DMODEL / TN), dim3(256), 0, stream,
                       Hb, W2T, b2, idx, texp, tval, ntiles, out, g * TPG);
  }
}

// Round 3
// 582.498 us; speedup vs baseline: 1.7283x; 1.1314x over previous
//
#include <hip/hip_runtime.h>
#include <math.h>

#define NTOK   32768
#define DMODEL 512
#define HIDDEN 2048
#define NEXP   16
#define TM     128
#define TN     128
#define BK     64
#define MAXT   272
#define PADN   (MAXT * TM)
#define CPAD   16              // pad per-expert counters to one 64B line

typedef short bf16x8 __attribute__((ext_vector_type(8)));
typedef float f32x4  __attribute__((ext_vector_type(4)));

__device__ __forceinline__ short f2bf(float f) {
  union { float f; unsigned int u; } v; v.f = f;
  unsigned int r = v.u + 0x7FFFu + ((v.u >> 16) & 1u);   // RNE
  return (short)(r >> 16);
}

__device__ __forceinline__ void gload_lds16(const void* g, void* l) {
  __builtin_amdgcn_global_load_lds(
      (const __attribute__((address_space(1))) void*)g,
      (__attribute__((address_space(3))) void*)l, 16, 0, 0);
}

// tanh-form GELU, overflow-safe. |err| vs exact erf GELU < 4e-4.
__device__ __forceinline__ float gelu_f(float v) {
  const float u = v * (0.7978845608f + 0.0356774081f * v * v);
  const float au = fabsf(u);
  const float z = __expf(-2.0f * au);
  float T = (1.0f - z) / (1.0f + z);
  T = copysignf(T, u);
  return 0.5f * v * (1.0f + T);
}

// ---------------------------------------------------------------- init
__global__ void init_kernel(int* counts, int* cursors) {
  counts[threadIdx.x] = 0; cursors[threadIdx.x] = 0;   // 256 padded ints each
}

// ---------------------------------------------------------------- route (+ x -> bf16)
// 1 wave per token; fp64 logit accumulation so routing decisions match the
// exact value (a flipped decision = O(1) output error). No atomics here.
__global__ __launch_bounds__(256) void route_kernel(
    const float* __restrict__ x, const float* __restrict__ Wr,
    const float* __restrict__ br, short* __restrict__ xb,
    int* __restrict__ leafArr) {
  const int w = threadIdx.x >> 6, l = threadIdx.x & 63;
  const int tok = blockIdx.x * 4 + w;
  const float4* xr = (const float4*)(x + (size_t)tok * DMODEL);
  float4 a0 = xr[l * 2], a1 = xr[l * 2 + 1];

  union { bf16x8 v; short s[8]; } u;
  u.s[0] = f2bf(a0.x); u.s[1] = f2bf(a0.y); u.s[2] = f2bf(a0.z); u.s[3] = f2bf(a0.w);
  u.s[4] = f2bf(a1.x); u.s[5] = f2bf(a1.y); u.s[6] = f2bf(a1.z); u.s[7] = f2bf(a1.w);
  *((bf16x8*)(xb + (size_t)tok * DMODEL) + l) = u.v;

  int leaf = 0;
  for (int d = 0; d < 4; ++d) {
    const int node = (1 << d) - 1 + leaf;
    const float4* wr4 = (const float4*)(Wr + (size_t)node * DMODEL);
    float4 b0 = wr4[l * 2], b1v = wr4[l * 2 + 1];
    double s = (double)a0.x * (double)b0.x + (double)a0.y * (double)b0.y +
               (double)a0.z * (double)b0.z + (double)a0.w * (double)b0.w +
               (double)a1.x * (double)b1v.x + (double)a1.y * (double)b1v.y +
               (double)a1.z * (double)b1v.z + (double)a1.w * (double)b1v.w;
    for (int off = 32; off; off >>= 1) s += __shfl_xor(s, off);
    double sel = s + (double)br[node];
    leaf = leaf * 2 + (sel > 0.0 ? 1 : 0);
  }
  if (l == 0) leafArr[tok] = leaf;
}

// ---------------------------------------------------------------- count
__global__ __launch_bounds__(256) void count_kernel(
    const int* __restrict__ leafArr, int* __restrict__ counts,
    int* __restrict__ idx) {
  __shared__ int lcnt[NEXP];
  const int tid = threadIdx.x;
  if (tid < NEXP) lcnt[tid] = 0;
  __syncthreads();
  const int tok = blockIdx.x * 256 + tid;
  atomicAdd(&lcnt[leafArr[tok]], 1);
  __syncthreads();
  if (tid < NEXP && lcnt[tid]) atomicAdd(&counts[tid * CPAD], lcnt[tid]);
  for (int i = blockIdx.x * 256 + tid; i < PADN; i += gridDim.x * 256) idx[i] = 0;
}

// ---------------------------------------------------------------- scan (1 block)
__global__ void scan_kernel(const int* __restrict__ counts, int* poff, int* ntiles,
                            int* texp, int* tval) {
  if (threadIdx.x == 0) {
    int po = 0, nt = 0;
    for (int e = 0; e < NEXP; ++e) {
      poff[e] = po;
      const int c = counts[e * CPAD];
      const int t = (c + TM - 1) >> 7;
      for (int i = 0; i < t; ++i) {
        texp[nt] = e;
        int v = c - i * TM; if (v > TM) v = TM;
        tval[nt] = v;
        ++nt;
      }
      po += t << 7;
    }
    poff[NEXP] = po;
    *ntiles = nt;
  }
}

// ---------------------------------------------------------------- scatter
__global__ __launch_bounds__(256) void scatter_kernel(
    const int* __restrict__ leafArr, const int* __restrict__ poff,
    int* cursors, int* __restrict__ idx) {
  __shared__ int lcnt[NEXP], lbase[NEXP];
  const int tid = threadIdx.x;
  if (tid < NEXP) lcnt[tid] = 0;
  __syncthreads();
  const int tok = blockIdx.x * 256 + tid;
  const int e = leafArr[tok];
  const int r = atomicAdd(&lcnt[e], 1);
  __syncthreads();
  if (tid < NEXP) lbase[tid] = lcnt[tid] ? atomicAdd(&cursors[tid * CPAD], lcnt[tid]) : 0;
  __syncthreads();
  idx[poff[e] + lbase[e] + r] = tok;
}

// ---------------------------------------------------------------- transpose+convert
__global__ void tconv_kernel(const float* __restrict__ src, short* __restrict__ dst,
                             int R, int C) {
  __shared__ float tile[32][33];
  const int tx = threadIdx.x, ty = threadIdx.y;
  const int c0 = blockIdx.x * 32, r0 = blockIdx.y * 32;
  const size_t eoff = (size_t)blockIdx.z * R * C;
  for (int i = 0; i < 4; ++i)
    tile[ty + i * 8][tx] = src[eoff + (size_t)(r0 + ty + i * 8) * C + c0 + tx];
  __syncthreads();
  for (int i = 0; i < 4; ++i)
    dst[eoff + (size_t)(c0 + ty + i * 8) * R + r0 + tx] = f2bf(tile[tx][ty + i * 8]);
}

// ================================================================ GEMM1
// H = GELU(Xg @ W1 + b1).  LDS tiles stored chunk-swizzled: row r, 16B-chunk c
// lands at slot (c ^ (r&7)) -> fragment ds_read_b128 is 2-way max (free).
__global__ __launch_bounds__(256) void gemm1_kernel(
    const short* __restrict__ Xb, const short* __restrict__ W1T,
    const float* __restrict__ b1, const int* __restrict__ idx,
    const int* __restrict__ texp, const int* __restrict__ ntiles,
    short* __restrict__ H, int g0) {
  const int lt = blockIdx.x;
  const int t = g0 + lt;
  if (t >= *ntiles) return;
  const int e = texp[t];
  const int c0 = blockIdx.y * TN;

  __shared__ short smem[TM * BK * 2];       // As | Bs, reused as C-tile at epilogue
  short* As = smem;
  short* Bs = smem + TM * BK;

  const int tid = threadIdx.x, w = tid >> 6, lane = tid & 63;
  const int q = lane >> 4, cc = lane & 15;
  const int wr = (w >> 1) * 64, wc = (w & 1) * 64;
  const int srow = lane >> 3;
  const int sk = ((lane & 7) ^ srow) * 8;   // swizzled global chunk for this lane

  f32x4 acc[4][4];
  const f32x4 zero = {0.f, 0.f, 0.f, 0.f};
  for (int mi = 0; mi < 4; ++mi)
    for (int ni = 0; ni < 4; ++ni) acc[mi][ni] = zero;

  for (int k0 = 0; k0 < DMODEL; k0 += BK) {
    __syncthreads();
    for (int ii = 0; ii < 4; ++ii) {
      const int i = w * 4 + ii;
      const int trow = i * 8 + srow;
      const int gt = idx[t * TM + trow];                    // gathered token
      gload_lds16(Xb + (size_t)gt * DMODEL + k0 + sk, As + i * 512);
      const int nn = c0 + i * 8 + srow;
      gload_lds16(W1T + ((size_t)e * HIDDEN + nn) * DMODEL + k0 + sk, Bs + i * 512);
    }
    __syncthreads();
    for (int ki = 0; ki < 2; ++ki) {
      const int ch = ki * 4 + q;
      const int sw = (ch ^ (cc & 7)) << 3;   // row&7 == cc&7 for all fragment rows
      bf16x8 af[4], bfv[4];
      for (int mi = 0; mi < 4; ++mi)
        af[mi] = *(const bf16x8*)(As + (wr + mi * 16 + cc) * BK + sw);
      for (int ni = 0; ni < 4; ++ni)
        bfv[ni] = *(const bf16x8*)(Bs + (wc + ni * 16 + cc) * BK + sw);
      for (int mi = 0; mi < 4; ++mi)
        for (int ni = 0; ni < 4; ++ni)
          acc[mi][ni] = __builtin_amdgcn_mfma_f32_16x16x32_bf16(af[mi], bfv[ni], acc[mi][ni], 0, 0, 0);
    }
  }

  // ---- epilogue: GELU -> swizzled LDS C-tile -> coalesced 16B H stores
  __syncthreads();
  short* Cs = smem;                         // [128][128] bf16, chunk-XOR-16 swizzled
  for (int ni = 0; ni < 4; ++ni) {
    const int col = wc + ni * 16 + cc;
    const float bv = b1[e * HIDDEN + c0 + col];
    for (int mi = 0; mi < 4; ++mi) {
      for (int r = 0; r < 4; ++r) {
        const int row = wr + mi * 16 + q * 4 + r;
        const float v = gelu_f(acc[mi][ni][r] + bv);
        Cs[row * 128 + ((((col >> 3) ^ (row & 15)) << 3) | (col & 7))] = f2bf(v);
      }
    }
  }
  __syncthreads();
  for (int it = 0; it < 8; ++it) {
    const int lin = tid + it * 256;         // 0..2047
    const int row = lin >> 4;
    const int s = lin & 15;
    const bf16x8 vv = *(const bf16x8*)(Cs + row * 128 + s * 8);
    const int ch = s ^ (row & 15);
    *(bf16x8*)(H + ((size_t)lt * TM + row) * HIDDEN + c0 + (ch << 3)) = vv;
  }
}

// ================================================================ GEMM2
// out[tok] = H @ W2 + b2, scattered by idx. f32 stores are full-line coalesced.
__global__ __launch_bounds__(256) void gemm2_kernel(
    const short* __restrict__ H, const short* __restrict__ W2T,
    const float* __restrict__ b2, const int* __restrict__ idx,
    const int* __restrict__ texp, const int* __restrict__ tval,
    const int* __restrict__ ntiles, float* __restrict__ out, int g0) {
  const int lt = blockIdx.x;
  const int t = g0 + lt;
  if (t >= *ntiles) return;
  const int e = texp[t];
  const int c0 = blockIdx.y * TN;   // 0..511 step 128

  __shared__ short smem[TM * BK * 2];
  short* As = smem;
  short* Bs = smem + TM * BK;

  const int tid = threadIdx.x, w = tid >> 6, lane = tid & 63;
  const int q = lane >> 4, cc = lane & 15;
  const int wr = (w >> 1) * 64, wc = (w & 1) * 64;
  const int srow = lane >> 3;
  const int sk = ((lane & 7) ^ srow) * 8;

  f32x4 acc[4][4];
  const f32x4 zero = {0.f, 0.f, 0.f, 0.f};
  for (int mi = 0; mi < 4; ++mi)
    for (int ni = 0; ni < 4; ++ni) acc[mi][ni] = zero;

  for (int k0 = 0; k0 < HIDDEN; k0 += BK) {
    __syncthreads();
    for (int ii = 0; ii < 4; ++ii) {
      const int i = w * 4 + ii;
      const int trow = i * 8 + srow;
      gload_lds16(H + ((size_t)lt * TM + trow) * HIDDEN + k0 + sk, As + i * 512);
      const int nn = c0 + i * 8 + srow;
      gload_lds16(W2T + ((size_t)e * DMODEL + nn) * HIDDEN + k0 + sk, Bs + i * 512);
    }
    __syncthreads();
    for (int ki = 0; ki < 2; ++ki) {
      const int ch = ki * 4 + q;
      const int sw = (ch ^ (cc & 7)) << 3;
      bf16x8 af[4], bfv[4];
      for (int mi = 0; mi < 4; ++mi)
        af[mi] = *(const bf16x8*)(As + (wr + mi * 16 + cc) * BK + sw);
      for (int ni = 0; ni < 4; ++ni)
        bfv[ni] = *(const bf16x8*)(Bs + (wc + ni * 16 + cc) * BK + sw);
      for (int mi = 0; mi < 4; ++mi)
        for (int ni = 0; ni < 4; ++ni)
          acc[mi][ni] = __builtin_amdgcn_mfma_f32_16x16x32_bf16(af[mi], bfv[ni], acc[mi][ni], 0, 0, 0);
    }
  }

  const int nv = tval[t];
  for (int ni = 0; ni < 4; ++ni) {
    const int col = c0 + wc + ni * 16 + cc;
    const float bv = b2[e * DMODEL + col];
    for (int mi = 0; mi < 4; ++mi) {
      for (int r = 0; r < 4; ++r) {
        const int row = wr + mi * 16 + q * 4 + r;
        if (row < nv) {
          const int tok = idx[t * TM + row];
          out[(size_t)tok * DMODEL + col] = acc[mi][ni][r] + bv;
        }
      }
    }
  }
}

// ---------------------------------------------------------------- host
extern "C" void kernel_launch(void* const* d_in, const int* in_sizes, int n_in,
                              void* d_out, int out_size, void* d_ws, size_t ws_size,
                              hipStream_t stream) {
  (void)in_sizes; (void)n_in; (void)out_size;
  const float* x  = (const float*)d_in[0];
  const float* Wr = (const float*)d_in[1];
  const float* br = (const float*)d_in[2];
  const float* W1 = (const float*)d_in[3];
  const float* b1 = (const float*)d_in[4];
  const float* W2 = (const float*)d_in[5];
  const float* b2 = (const float*)d_in[6];
  float* out = (float*)d_out;
  char* ws = (char*)d_ws;

  int* counts  = (int*)(ws + 0);        // 256 ints, padded x16
  int* cursors = (int*)(ws + 1024);     // 256 ints, padded x16
  int* poff    = (int*)(ws + 2048);
  int* ntiles  = (int*)(ws + 2304);
  int* texp    = (int*)(ws + 4096);
  int* tval    = (int*)(ws + 8192);
  int* leafA   = (int*)(ws + 16384);
  int* idx     = (int*)(ws + 16384 + 131072);

  const size_t MB32 = 33554432ull;
  short* Xb  = (short*)(ws + (1ull << 20));
  short* W1T = (short*)(ws + (1ull << 20) + MB32);
  short* W2T = (short*)(ws + (1ull << 20) + 2 * MB32);
  short* Hb  = (short*)(ws + (1ull << 20) + 3 * MB32);
  const size_t o_h = (1ull << 20) + 3 * MB32;
  const size_t perTile = (size_t)TM * HIDDEN * sizeof(short);   // 512 KB

  int TPG = MAXT;
  if (ws_size < o_h + (size_t)MAXT * perTile) {
    size_t avail = ws_size > o_h ? ws_size - o_h : 0;
    TPG = (int)(avail / perTile);
    if (TPG < 1) TPG = 1;
  }
  const int ngroups = (MAXT + TPG - 1) / TPG;

  hipLaunchKernelGGL(init_kernel,    dim3(1),          dim3(256),   0, stream, counts, cursors);
  hipLaunchKernelGGL(route_kernel,   dim3(NTOK / 4),   dim3(256),   0, stream, x, Wr, br, Xb, leafA);
  hipLaunchKernelGGL(count_kernel,   dim3(NTOK / 256), dim3(256),   0, stream, leafA, counts, idx);
  hipLaunchKernelGGL(scan_kernel,    dim3(1),          dim3(64),    0, stream, counts, poff, ntiles, texp, tval);
  hipLaunchKernelGGL(scatter_kernel, dim3(NTOK / 256), dim3(256),   0, stream, leafA, poff, cursors, idx);
  hipLaunchKernelGGL(tconv_kernel,   dim3(64, 16, 16), dim3(32, 8), 0, stream, W1, W1T, DMODEL, HIDDEN);
  hipLaunchKernelGGL(tconv_kernel,   dim3(16, 64, 16), dim3(32, 8), 0, stream, W2, W2T, HIDDEN, DMODEL);

  for (int g = 0; g < ngroups; ++g) {
    hipLaunchKernelGGL(gemm1_kernel, dim3(TPG, HIDDEN / TN), dim3(256), 0, stream,
                       Xb, W1T, b1, idx, texp, ntiles, Hb, g * TPG);
    hipLaunchKernelGGL(gemm2_kernel, dim3(TPG, DMODEL / TN), dim3(256), 0, stream,
                       Hb, W2T, b2, idx, texp, tval, ntiles, out, g * TPG);
  }
}